// Round 15
// baseline (293.706 us; speedup 1.0000x reference)
//
#include <hip/hip_runtime.h>
#include <hip/hip_bf16.h>
#include <math.h>

using bf16 = __hip_bfloat16;
typedef __bf16 bf16x8 __attribute__((ext_vector_type(8)));
typedef float f32x4 __attribute__((ext_vector_type(4)));

static constexpr int B_ = 2, T_ = 2048, D_ = 1024, H_ = 16, HD_ = 64, FH_ = 2752;
static constexpr int BT = B_ * T_;  // 4096

struct __align__(8)  bh4 { bf16 h[4]; };
struct __align__(16) bh8 { bf16 h[8]; };

#define DEV static __device__ __forceinline__

DEV float b2f(bf16 v) { return __bfloat162float(v); }
DEV bf16  f2b(float v) { return __float2bfloat16(v); }
DEV __bf16 f2bb(float f) { __hip_bfloat16 h = __float2bfloat16(f); return *reinterpret_cast<__bf16*>(&h); }
DEV float sigmoidf_(float x) { return 1.0f / (1.0f + __expf(-x)); }

DEV void load4f(const bf16* p, float* v) {
    bh4 t = *reinterpret_cast<const bh4*>(p);
#pragma unroll
    for (int i = 0; i < 4; ++i) v[i] = b2f(t.h[i]);
}
DEV void load4f(const float* p, float* v) {
    float4 t = *reinterpret_cast<const float4*>(p);
    v[0] = t.x; v[1] = t.y; v[2] = t.z; v[3] = t.w;
}
DEV void store4(float* p, const float* v) {
    float4 t; t.x = v[0]; t.y = v[1]; t.z = v[2]; t.w = v[3];
    *reinterpret_cast<float4*>(p) = t;
}
DEV float waveReduceSum(float v) {
#pragma unroll
    for (int m = 32; m; m >>= 1) v += __shfl_xor(v, m);
    return v;
}

// async global->LDS, 16B per lane; lds base wave-uniform, global addr per-lane
DEV void gl_lds16(const bf16* g, bf16* lds_base) {
    __builtin_amdgcn_global_load_lds(
        (const __attribute__((address_space(1))) void*)g,
        (__attribute__((address_space(3))) void*)lds_base, 16, 0, 0);
}

// ---------------- RoPE tables ----------------
__global__ __launch_bounds__(256) void k_rope_tables(float* __restrict__ cost, float* __restrict__ sint) {
    int idx = blockIdx.x * 256 + threadIdx.x;
    if (idx >= T_ * 32) return;
    int t = idx >> 5, j = idx & 31;
    float inv = powf(10000.0f, -(float)j * (1.0f / 32.0f));
    float f = (float)t * inv;
    cost[idx] = cosf(f);
    sint[idx] = sinf(f);
}

// ---------------- weight f32 -> bf16 ----------------
__global__ __launch_bounds__(256) void k_f2b(const float* __restrict__ in, bf16* __restrict__ out, int n8) {
    int i = blockIdx.x * 256 + threadIdx.x;
    if (i >= n8) return;
    const float4* p = reinterpret_cast<const float4*>(in + (size_t)i * 8);
    float4 a = p[0], b = p[1];
    bh8 o;
    o.h[0] = f2b(a.x); o.h[1] = f2b(a.y); o.h[2] = f2b(a.z); o.h[3] = f2b(a.w);
    o.h[4] = f2b(b.x); o.h[5] = f2b(b.y); o.h[6] = f2b(b.z); o.h[7] = f2b(b.w);
    *reinterpret_cast<bh8*>(out + (size_t)i * 8) = o;
}

// ---- w1/w3 -> 16-row-interleaved bf16 ----
__global__ __launch_bounds__(256) void k_f2b_pair(const float* __restrict__ w1, const float* __restrict__ w3,
                                                  bf16* __restrict__ outp, int n8tot) {
    int i = blockIdx.x * 256 + threadIdx.x;
    if (i >= n8tot) return;
    int r = i >> 7, c8 = i & 127;
    int sel = (r >> 4) & 1;
    int j = ((r >> 5) << 4) | (r & 15);
    const float* src = (sel ? w3 : w1) + (size_t)j * D_ + c8 * 8;
    float4 a = reinterpret_cast<const float4*>(src)[0];
    float4 b = reinterpret_cast<const float4*>(src)[1];
    bh8 o;
    o.h[0] = f2b(a.x); o.h[1] = f2b(a.y); o.h[2] = f2b(a.z); o.h[3] = f2b(a.w);
    o.h[4] = f2b(b.x); o.h[5] = f2b(b.y); o.h[6] = f2b(b.z); o.h[7] = f2b(b.w);
    *reinterpret_cast<bh8*>(outp + (size_t)r * D_ + c8 * 8) = o;
}

// ---------------- RMSNorm over D=1024 (f32 in, bf16 out) ----------------
__global__ __launch_bounds__(256) void k_rmsnorm(const float* __restrict__ x, const float* __restrict__ w,
                                                 bf16* __restrict__ out) {
    int row = blockIdx.x, tid = threadIdx.x;
    const float* xr = x + (size_t)row * D_;
    int base = tid * 4;
    float v[4];
    load4f(xr + base, v);
    float ss = v[0]*v[0] + v[1]*v[1] + v[2]*v[2] + v[3]*v[3];
    ss = waveReduceSum(ss);
    __shared__ float red[4];
    if ((tid & 63) == 0) red[tid >> 6] = ss;
    __syncthreads();
    ss = red[0] + red[1] + red[2] + red[3];
    float r = rsqrtf(ss * (1.0f / D_) + 1e-6f);
    float wv[4];
    load4f(w + base, wv);
    bh4 o;
#pragma unroll
    for (int i = 0; i < 4; ++i) o.h[i] = f2b(v[i] * r * wv[i]);
    *reinterpret_cast<bh4*>(out + (size_t)row * D_ + base) = o;
}

// ======== GEMM 256x128, BK=32, 512 threads (8 waves 4x2) ========
// Depth-3 ring, SINGLE barrier per K-step: stage(t+2) targets buf[(t+2)%3] != read buf[t%3],
// so it issues right after the barrier and overlaps compute. Per-wave 3 gl_lds16/stage ->
// vmcnt(3) leaves next stage in flight. Safety: a wave passes bar(t) only after its step-(t-1)
// ds_reads are register-complete, so post-bar stages into buf[(t+2)%3] cannot race.
// LDS[row][c] holds global chunk c ^ ((row>>1)&3) -> conflict-free ds_read_b128.
// EPI=0: C=acc. EPI=1: paired SwiGLU columns -> g[M][N/2].
template <int EPI>
__global__ __launch_bounds__(512) void k_gemm256(const bf16* __restrict__ A, const bf16* __restrict__ W,
                                                 bf16* __restrict__ C, int M, int N, int K) {
    __shared__ bf16 sA[3][256 * 32];
    __shared__ bf16 sB[3][128 * 32];
    int tid = threadIdx.x, lane = tid & 63, wid = tid >> 6;
    int m0 = blockIdx.x * 256, n0 = blockIdx.y * 128;
    int wr = wid >> 1, wc = wid & 1;
    int l16 = lane & 15, lg = lane >> 4;
    int srow = lane >> 2;
    int scol = ((lane & 3) ^ ((lane >> 3) & 3)) * 8;   // inverse-swizzled global chunk
    int rchunk = (lg ^ ((l16 >> 1) & 3)) * 8;          // swizzled fragment read chunk

    f32x4 acc[4][4] = {};

#define STAGE(buf, k0)                                                                   \
    {                                                                                    \
        _Pragma("unroll")                                                                \
        for (int c = 0; c < 2; ++c) {                                                    \
            int r0 = wid * 32 + c * 16;                                                  \
            gl_lds16(&A[(size_t)(m0 + r0 + srow) * K + (k0) + scol], &sA[buf][r0 * 32]); \
        }                                                                                \
        {                                                                                \
            int r0 = wid * 16;                                                           \
            gl_lds16(&W[(size_t)(n0 + r0 + srow) * K + (k0) + scol], &sB[buf][r0 * 32]); \
        }                                                                                \
    }

    int nk = K >> 5;
    STAGE(0, 0);
    if (nk > 1) STAGE(1, 32);
    int cur = 0;
    for (int t = 0; t < nk; ++t) {
        if (t + 1 < nk) { asm volatile("s_waitcnt vmcnt(3)" ::: "memory"); }
        else            { asm volatile("s_waitcnt vmcnt(0)" ::: "memory"); }
        __builtin_amdgcn_s_barrier();
        __builtin_amdgcn_sched_barrier(0);
        if (t + 2 < nk) {
            int nbuf = cur + 2; if (nbuf >= 3) nbuf -= 3;
            STAGE(nbuf, (t + 2) * 32);
        }
        bf16x8 af[4], bfr[4];
#pragma unroll
        for (int m = 0; m < 4; ++m)
            af[m] = *reinterpret_cast<const bf16x8*>(&sA[cur][(wr * 64 + m * 16 + l16) * 32 + rchunk]);
#pragma unroll
        for (int n = 0; n < 4; ++n)
            bfr[n] = *reinterpret_cast<const bf16x8*>(&sB[cur][(wc * 64 + n * 16 + l16) * 32 + rchunk]);
        __builtin_amdgcn_s_setprio(1);
#pragma unroll
        for (int m = 0; m < 4; ++m)
#pragma unroll
            for (int n = 0; n < 4; ++n)
                acc[m][n] = __builtin_amdgcn_mfma_f32_16x16x32_bf16(af[m], bfr[n], acc[m][n], 0, 0, 0);
        __builtin_amdgcn_s_setprio(0);
        cur = (cur + 1 == 3) ? 0 : cur + 1;
    }
#undef STAGE

    int rbase = m0 + wr * 64;
    if (EPI == 1) {
        int Ng = N >> 1;
        int gbase = (n0 >> 1) + wc * 32;
#pragma unroll
        for (int m = 0; m < 4; ++m) {
#pragma unroll
            for (int n2 = 0; n2 < 2; ++n2) {
                int gcol = gbase + n2 * 16 + l16;
#pragma unroll
                for (int r = 0; r < 4; ++r) {
                    int row = rbase + m * 16 + lg * 4 + r;
                    float a1 = acc[m][n2 * 2][r];
                    float a3 = acc[m][n2 * 2 + 1][r];
                    C[(size_t)row * Ng + gcol] = f2b(a1 * sigmoidf_(a1) * a3);
                }
            }
        }
    } else {
        int cbase = n0 + wc * 64;
#pragma unroll
        for (int m = 0; m < 4; ++m) {
#pragma unroll
            for (int n = 0; n < 4; ++n) {
                int col = cbase + n * 16 + l16;
#pragma unroll
                for (int r = 0; r < 4; ++r) {
                    int row = rbase + m * 16 + lg * 4 + r;
                    C[(size_t)row * N + col] = f2b(acc[m][n][r]);
                }
            }
        }
    }
}

// ======== GEMM 128x64 (wo, w2), 256 threads (4 waves), depth-3 single-barrier ring ========
__global__ __launch_bounds__(256) void k_gemm64(const bf16* __restrict__ A, const bf16* __restrict__ W,
                                                bf16* __restrict__ C, int M, int N, int K) {
    __shared__ bf16 sA[3][128 * 32];
    __shared__ bf16 sB[3][64 * 32];
    int tid = threadIdx.x, lane = tid & 63, wid = tid >> 6;
    int m0 = blockIdx.x * 128, n0 = blockIdx.y * 64;
    int wr = wid;
    int l16 = lane & 15, lg = lane >> 4;
    int srow = lane >> 2;
    int scol = ((lane & 3) ^ ((lane >> 3) & 3)) * 8;
    int rchunk = (lg ^ ((l16 >> 1) & 3)) * 8;

    f32x4 acc[2][4] = {};

#define STAGE(buf, k0)                                                                   \
    {                                                                                    \
        _Pragma("unroll")                                                                \
        for (int c = 0; c < 2; ++c) {                                                    \
            int r0 = wid * 32 + c * 16;                                                  \
            gl_lds16(&A[(size_t)(m0 + r0 + srow) * K + (k0) + scol], &sA[buf][r0 * 32]); \
        }                                                                                \
        {                                                                                \
            int r0 = wid * 16;                                                           \
            gl_lds16(&W[(size_t)(n0 + r0 + srow) * K + (k0) + scol], &sB[buf][r0 * 32]); \
        }                                                                                \
    }

    int nk = K >> 5;
    STAGE(0, 0);
    if (nk > 1) STAGE(1, 32);
    int cur = 0;
    for (int t = 0; t < nk; ++t) {
        if (t + 1 < nk) { asm volatile("s_waitcnt vmcnt(3)" ::: "memory"); }
        else            { asm volatile("s_waitcnt vmcnt(0)" ::: "memory"); }
        __builtin_amdgcn_s_barrier();
        __builtin_amdgcn_sched_barrier(0);
        if (t + 2 < nk) {
            int nbuf = cur + 2; if (nbuf >= 3) nbuf -= 3;
            STAGE(nbuf, (t + 2) * 32);
        }
        bf16x8 af[2], bfr[4];
#pragma unroll
        for (int m = 0; m < 2; ++m)
            af[m] = *reinterpret_cast<const bf16x8*>(&sA[cur][(wr * 32 + m * 16 + l16) * 32 + rchunk]);
#pragma unroll
        for (int n = 0; n < 4; ++n)
            bfr[n] = *reinterpret_cast<const bf16x8*>(&sB[cur][(n * 16 + l16) * 32 + rchunk]);
        __builtin_amdgcn_s_setprio(1);
#pragma unroll
        for (int m = 0; m < 2; ++m)
#pragma unroll
            for (int n = 0; n < 4; ++n)
                acc[m][n] = __builtin_amdgcn_mfma_f32_16x16x32_bf16(af[m], bfr[n], acc[m][n], 0, 0, 0);
        __builtin_amdgcn_s_setprio(0);
        cur = (cur + 1 == 3) ? 0 : cur + 1;
    }
#undef STAGE

    int rbase = m0 + wid * 32;
#pragma unroll
    for (int m = 0; m < 2; ++m) {
#pragma unroll
        for (int n = 0; n < 4; ++n) {
            int col = n0 + n * 16 + l16;
#pragma unroll
            for (int r = 0; r < 4; ++r) {
                int row = rbase + m * 16 + lg * 4 + r;
                C[(size_t)row * N + col] = f2b(acc[m][n][r]);
            }
        }
    }
}

// ---------------- per-head RMSNorm + RoPE ----------------
__global__ __launch_bounds__(256) void k_qk_norm_rope(const bf16* __restrict__ qin, const float* __restrict__ wn,
                                                      const float* __restrict__ cost, const float* __restrict__ sint,
                                                      bf16* __restrict__ qout, float scale, int ld, int off) {
    int tid = threadIdx.x;
    int g = blockIdx.x * 4 + (tid >> 6);
    int d = tid & 63;
    int h = g % H_, t = (g / H_) % T_, b = g / (H_ * T_);
    float v = b2f(qin[(size_t)(b * T_ + t) * ld + off + h * HD_ + d]);
    float ss = waveReduceSum(v * v);
    float r = rsqrtf(ss * (1.0f / HD_) + 1e-6f);
    float xn = v * r * wn[d];
    float p = __shfl_xor(xn, 32);
    float c = cost[t * 32 + (d & 31)], s = sint[t * 32 + (d & 31)];
    float o = (d < 32) ? (xn * c - p * s) : (xn * c + p * s);
    qout[((size_t)(b * H_ + h) * T_ + t) * HD_ + d] = f2b(o * scale);
}

// ---------------- V: strided (B*T, ld)+off -> (B,H,HD,T) ----------------
__global__ __launch_bounds__(256) void k_v_transpose(const bf16* __restrict__ vin, bf16* __restrict__ vt,
                                                     int ld, int off) {
    __shared__ bf16 tile[64][72];
    int tid = threadIdx.x;
    int bh = blockIdx.y;
    int t0 = blockIdx.x * 64;
    int b = bh >> 4, h = bh & 15;
#pragma unroll
    for (int i = 0; i < 16; ++i) {
        int lin = i * 256 + tid;
        int tl = lin >> 6, d = lin & 63;
        tile[tl][d] = vin[(size_t)(b * T_ + t0 + tl) * ld + off + h * HD_ + d];
    }
    __syncthreads();
#pragma unroll
    for (int i = 0; i < 16; ++i) {
        int lin = i * 256 + tid;
        int d = lin >> 6, tl = lin & 63;
        vt[((size_t)bh * HD_ + d) * T_ + t0 + tl] = tile[tl][d];
    }
}

// ---------------- Flash v3 + XCD swizzle + T13 defer-max (THR=8) ----------------
template <bool MASKED>
DEV void fa3_tile(const bf16* __restrict__ kl, const bf16* __restrict__ vl,
                  int l16, int lg, int qloc,
                  const bf16x8 qf0, const bf16x8 qf1,
                  f32x4* acc, float& m_r, float& l_r) {
    f32x4 s[8];
#pragma unroll
    for (int n = 0; n < 8; ++n) {
        int kv = n * 16 + l16;
        bf16x8 kf0 = *reinterpret_cast<const bf16x8*>(&kl[kv * 64 + (((lg ^ kv) & 7) << 3)]);
        bf16x8 kf1 = *reinterpret_cast<const bf16x8*>(&kl[kv * 64 + ((((4 + lg) ^ kv) & 7) << 3)]);
        f32x4 t = {};
        t = __builtin_amdgcn_mfma_f32_16x16x32_bf16(kf0, qf0, t, 0, 0, 0);
        t = __builtin_amdgcn_mfma_f32_16x16x32_bf16(kf1, qf1, t, 0, 0, 0);
        s[n] = t;
    }
    if (MASKED) {
#pragma unroll
        for (int n = 0; n < 8; ++n)
#pragma unroll
            for (int r = 0; r < 4; ++r)
                if (n * 16 + lg * 4 + r > qloc) s[n][r] = -INFINITY;
    }
    float mx = -INFINITY;
#pragma unroll
    for (int n = 0; n < 8; ++n)
#pragma unroll
        for (int r = 0; r < 4; ++r) mx = fmaxf(mx, s[n][r]);
    mx = fmaxf(mx, __shfl_xor(mx, 16));
    mx = fmaxf(mx, __shfl_xor(mx, 32));
    if (!__all(mx - m_r <= 8.0f)) {
        float mnew = fmaxf(m_r, mx);
        float corr = __expf(m_r - mnew);
        m_r = mnew;
        l_r *= corr;
#pragma unroll
        for (int np = 0; np < 4; ++np) acc[np] = acc[np] * corr;
    }
    float ps = 0.0f;
#pragma unroll
    for (int n = 0; n < 8; ++n)
#pragma unroll
        for (int r = 0; r < 4; ++r) {
            float e = __expf(s[n][r] - m_r);
            s[n][r] = e;
            ps += e;
        }
    l_r += ps;

    bf16x8 pb[4];
#pragma unroll
    for (int n2 = 0; n2 < 4; ++n2)
#pragma unroll
        for (int j = 0; j < 8; ++j)
            pb[n2][j] = f2bb(s[2 * n2 + (j >> 2)][j & 3]);

    int d15 = l16;
    int eoff = (lg & 1) * 4;
#pragma unroll
    for (int n2 = 0; n2 < 4; ++n2) {
        int c0 = (n2 * 4 + (lg >> 1));
        int c1 = c0 + 2;
#pragma unroll
        for (int np = 0; np < 4; ++np) {
            int d = np * 16 + l16;
            union { bf16x8 v; bh4 q[2]; } u;
            u.q[0] = *reinterpret_cast<const bh4*>(&vl[d * 128 + ((c0 ^ d15) << 3) + eoff]);
            u.q[1] = *reinterpret_cast<const bh4*>(&vl[d * 128 + ((c1 ^ d15) << 3) + eoff]);
            acc[np] = __builtin_amdgcn_mfma_f32_16x16x32_bf16(u.v, pb[n2], acc[np], 0, 0, 0);
        }
    }
}

__global__ __launch_bounds__(256) void k_flash(const bf16* __restrict__ Q, const bf16* __restrict__ Kk,
                                               const bf16* __restrict__ Vt, bf16* __restrict__ Out) {
    __shared__ bf16 kl[128 * 64];
    __shared__ bf16 vl[64 * 128];
    int tid = threadIdx.x, lane = tid & 63, w = tid >> 6;
    int l16 = lane & 15, lg = lane >> 4;
    int L = blockIdx.x;
    int xcd = L & 7, m = L >> 3;
    int bh = xcd * 4 + (m & 3);
    int qi = (T_ / 128 - 1) - (m >> 2);
    int q0 = qi * 128;
    int b = bh >> 4, h = bh & 15;
    const bf16* qb = Q + (size_t)bh * T_ * HD_;
    const bf16* kb = Kk + (size_t)bh * T_ * HD_;
    const bf16* vb = Vt + (size_t)bh * HD_ * T_;

    bf16x8 qfr[2][2];
#pragma unroll
    for (int f = 0; f < 2; ++f) {
        int qrow = q0 + w * 32 + f * 16 + l16;
        const bf16* qp = qb + (size_t)qrow * HD_ + lg * 8;
        qfr[f][0] = *reinterpret_cast<const bf16x8*>(qp);
        qfr[f][1] = *reinterpret_cast<const bf16x8*>(qp + 32);
    }
    f32x4 acc[2][4] = {};
    float m_r[2] = {-INFINITY, -INFINITY};
    float l_r[2] = {0.0f, 0.0f};

    for (int kv0 = 0; kv0 <= q0; kv0 += 128) {
        __syncthreads();
#pragma unroll
        for (int i = 0; i < 4; ++i) {
            int idx = i * 256 + tid;
            int kv = idx >> 3, c = idx & 7;
            *reinterpret_cast<bh8*>(&kl[kv * 64 + (((c ^ kv) & 7) << 3)]) =
                *reinterpret_cast<const bh8*>(&kb[(size_t)(kv0 + kv) * HD_ + c * 8]);
        }
#pragma unroll
        for (int i = 0; i < 4; ++i) {
            int idx = i * 256 + tid;
            int d = idx >> 4, c = idx & 15;
            *reinterpret_cast<bh8*>(&vl[d * 128 + (((c ^ d) & 15) << 3)]) =
                *reinterpret_cast<const bh8*>(&vb[(size_t)d * T_ + kv0 + c * 8]);
        }
        __syncthreads();
        if (kv0 == q0) {
#pragma unroll
            for (int f = 0; f < 2; ++f)
                fa3_tile<true>(kl, vl, l16, lg, w * 32 + f * 16 + l16,
                               qfr[f][0], qfr[f][1], acc[f], m_r[f], l_r[f]);
        } else {
#pragma unroll
            for (int f = 0; f < 2; ++f)
                fa3_tile<false>(kl, vl, l16, lg, 0,
                                qfr[f][0], qfr[f][1], acc[f], m_r[f], l_r[f]);
        }
    }
#pragma unroll
    for (int f = 0; f < 2; ++f) {
        float lt = l_r[f];
        lt += __shfl_xor(lt, 16);
        lt += __shfl_xor(lt, 32);
        float inv = 1.0f / lt;
        int qrow = q0 + w * 32 + f * 16 + l16;
#pragma unroll
        for (int np = 0; np < 4; ++np) {
            bh4 o;
#pragma unroll
            for (int r = 0; r < 4; ++r) o.h[r] = f2b(acc[f][np][r] * inv);
            *reinterpret_cast<bh4*>(&Out[(size_t)(b * T_ + qrow) * D_ + h * HD_ + np * 16 + lg * 4]) = o;
        }
    }
}

// ---------------- delta_res (optionally fused with following RMSNorm) ----------------
template <int WRITE_XM>
__global__ __launch_bounds__(256) void k_delta_res(const float* __restrict__ x, const bf16* __restrict__ h,
                                                   const float* __restrict__ gn_w, const float* __restrict__ g_w,
                                                   const float* __restrict__ g_b, const float* __restrict__ wv_w,
                                                   float* __restrict__ out,
                                                   bf16* __restrict__ xm_out, const float* __restrict__ mlp_w) {
    int row = blockIdx.x, tid = threadIdx.x;
    int base = tid * 4;
    float xv[4], hv[4], gnv[4], gwv[4], wvv[4];
    load4f(x + (size_t)row * D_ + base, xv);
    load4f(h + (size_t)row * D_ + base, hv);
    load4f(gn_w + base, gnv);
    load4f(g_w + base, gwv);
    load4f(wv_w + base, wvv);
    float s_h2 = 0, s_x2 = 0, s_xg = 0, s_xv = 0, s_hx = 0;
#pragma unroll
    for (int i = 0; i < 4; ++i) {
        s_h2 += hv[i] * hv[i];
        s_x2 += xv[i] * xv[i];
        s_xg += xv[i] * gnv[i] * gwv[i];
        s_xv += xv[i] * wvv[i];
        s_hx += hv[i] * xv[i];
    }
    s_h2 = waveReduceSum(s_h2); s_x2 = waveReduceSum(s_x2); s_xg = waveReduceSum(s_xg);
    s_xv = waveReduceSum(s_xv); s_hx = waveReduceSum(s_hx);
    __shared__ float red[4][5];
    int wid = tid >> 6;
    if ((tid & 63) == 0) {
        red[wid][0] = s_h2; red[wid][1] = s_x2; red[wid][2] = s_xg;
        red[wid][3] = s_xv; red[wid][4] = s_hx;
    }
    __syncthreads();
    s_h2 = red[0][0] + red[1][0] + red[2][0] + red[3][0];
    s_x2 = red[0][1] + red[1][1] + red[2][1] + red[3][1];
    s_xg = red[0][2] + red[1][2] + red[2][2] + red[3][2];
    s_xv = red[0][3] + red[1][3] + red[2][3] + red[3][3];
    s_hx = red[0][4] + red[1][4] + red[2][4] + red[3][4];

    float r = rsqrtf(s_x2 * (1.0f / D_) + 1e-6f);
    float logit = r * s_xg + g_b[0];
    float beta = 2.0f * sigmoidf_(logit);
    float vsig = sigmoidf_(s_xv);
    float nrm = sqrtf(s_h2);
    float ks = (1.0f / 32.0f) / fmaxf(nrm, 1e-6f);
    float coef = beta * (vsig - ks * s_hx) * ks;
    float o[4];
#pragma unroll
    for (int i = 0; i < 4; ++i) o[i] = xv[i] + coef * hv[i];
    store4(out + (size_t)row * D_ + base, o);

    if (WRITE_XM) {
        float s2 = o[0]*o[0] + o[1]*o[1] + o[2]*o[2] + o[3]*o[3];
        s2 = waveReduceSum(s2);
        __shared__ float red2[4];
        __syncthreads();
        if ((tid & 63) == 0) red2[wid] = s2;
        __syncthreads();
        s2 = red2[0] + red2[1] + red2[2] + red2[3];
        float rr = rsqrtf(s2 * (1.0f / D_) + 1e-6f);
        float mw[4];
        load4f(mlp_w + base, mw);
        bh4 ob;
#pragma unroll
        for (int i = 0; i < 4; ++i) ob.h[i] = f2b(o[i] * rr * mw[i]);
        *reinterpret_cast<bh4*>(xm_out + (size_t)row * D_ + base) = ob;
    }
}

extern "C" void kernel_launch(void* const* d_in, const int* in_sizes, int n_in,
                              void* d_out, int out_size, void* d_ws, size_t ws_size,
                              hipStream_t stream) {
    const float* x       = (const float*)d_in[0];
    const float* wq      = (const float*)d_in[1];
    const float* wk      = (const float*)d_in[2];
    const float* wv      = (const float*)d_in[3];
    const float* wo      = (const float*)d_in[4];
    const float* qn_w    = (const float*)d_in[5];
    const float* kn_w    = (const float*)d_in[6];
    const float* attn_nw = (const float*)d_in[7];
    const float* g1_nw   = (const float*)d_in[8];
    const float* g1_w    = (const float*)d_in[9];
    const float* g1_b    = (const float*)d_in[10];
    const float* wv1     = (const float*)d_in[11];
    const float* mlp_nw  = (const float*)d_in[12];
    const float* w1      = (const float*)d_in[13];
    const float* w2      = (const float*)d_in[14];
    const float* w3      = (const float*)d_in[15];
    const float* g2_nw   = (const float*)d_in[16];
    const float* g2_w    = (const float*)d_in[17];
    const float* g2_b    = (const float*)d_in[18];
    const float* wv2     = (const float*)d_in[19];
    float* out = (float*)d_out;

    char* ws = (char*)d_ws;
    const size_t KB = 1024;
    const size_t MB = 1024 * 1024;
    float* cost = (float*)(ws);                        // 256 KB
    float* sint = (float*)(ws + 256 * KB);             // 256 KB
    bf16* XC = (bf16*)(ws + 512 * KB);                 // 8MB: xc -> wo_bf16 -> xm -> hmlp
    bf16* Bb = (bf16*)(ws + 512 * KB + 8  * MB);       // Bb..Db 24MB: qkv -> attn_out -> wpair/w2b
    bf16* Cb = (bf16*)(ws + 512 * KB + 16 * MB);       // 8MB: h_attn
    bf16* Db = (bf16*)(ws + 512 * KB + 24 * MB);       // 8MB: w2 bf16
    bf16* Eb = (bf16*)(ws + 512 * KB + 32 * MB);       // Eb..Gb 24MB: wqkv -> Qr/Kr/Vt -> g
    bf16* Fb = (bf16*)(ws + 512 * KB + 40 * MB);
    bf16* Gb = (bf16*)(ws + 512 * KB + 48 * MB);
    float* x1 = (float*)(ws + 512 * KB + 56 * MB);     // 16MB f32

    bf16* wqkv = Eb;
    bf16* qkv  = Bb;
    bf16* wbo  = XC;
    bf16* attn_out = Bb;
    bf16* wpair = Bb;
    bf16* w2b  = Db;
    bf16* g    = Eb;
    bf16* hmlp = XC;

    const int nDD = D_ * D_ / 8, nFD = FH_ * D_ / 8;
    dim3 blk(256);

    k_rope_tables<<<dim3((T_ * 32) / 256), blk, 0, stream>>>(cost, sint);

    k_rmsnorm<<<dim3(BT), blk, 0, stream>>>(x, attn_nw, XC);
    k_f2b<<<dim3((nDD + 255) / 256), blk, 0, stream>>>(wq, wqkv, nDD);
    k_f2b<<<dim3((nDD + 255) / 256), blk, 0, stream>>>(wk, wqkv + (size_t)D_ * D_, nDD);
    k_f2b<<<dim3((nDD + 255) / 256), blk, 0, stream>>>(wv, wqkv + (size_t)2 * D_ * D_, nDD);

    // fused QKV GEMM: 256x128 tiles, grid (16, 24)
    k_gemm256<0><<<dim3(16, 24), dim3(512), 0, stream>>>(XC, wqkv, qkv, BT, 3 * D_, D_);

    k_qk_norm_rope<<<dim3(BT * H_ / 4), blk, 0, stream>>>(qkv, qn_w, cost, sint, Eb, 0.125f, 3 * D_, 0);
    k_qk_norm_rope<<<dim3(BT * H_ / 4), blk, 0, stream>>>(qkv, kn_w, cost, sint, Fb, 1.0f, 3 * D_, D_);
    k_v_transpose<<<dim3(T_ / 64, B_ * H_), blk, 0, stream>>>(qkv, Gb, 3 * D_, 2 * D_);

    k_f2b<<<dim3((nDD + 255) / 256), blk, 0, stream>>>(wo, wbo, nDD);
    k_flash<<<dim3((T_ / 128) * B_ * H_), blk, 0, stream>>>(Eb, Fb, Gb, attn_out);

    // h_attn = attn_out @ wo^T : 128x64 tiles, grid (32, 16)
    k_gemm64<<<dim3(32, 16), blk, 0, stream>>>(attn_out, wbo, Cb, BT, D_, D_);

    // x1 = delta_res(x, h_attn)  (+ fused xm = rmsnorm(x1, mlp_nw) -> XC)
    k_delta_res<1><<<dim3(BT), blk, 0, stream>>>(x, Cb, g1_nw, g1_w, g1_b, wv1, x1, XC, mlp_nw);

    k_f2b_pair<<<dim3((2 * nFD + 255) / 256), blk, 0, stream>>>(w1, w3, wpair, 2 * nFD);
    k_f2b<<<dim3((nFD + 255) / 256), blk, 0, stream>>>(w2, w2b, nFD);

    // g = silu(xm@w1^T)*(xm@w3^T): 256x128 tiles, grid (16, 43)
    k_gemm256<1><<<dim3(16, 43), dim3(512), 0, stream>>>(XC, wpair, g, BT, 2 * FH_, D_);

    // h_mlp = g @ w2^T : 128x64, grid (32, 16)
    k_gemm64<<<dim3(32, 16), blk, 0, stream>>>(g, w2b, hmlp, BT, D_, FH_);

    // out = delta_res(x1, h_mlp)
    k_delta_res<0><<<dim3(BT), blk, 0, stream>>>(x1, hmlp, g2_nw, g2_w, g2_b, wv2, out, nullptr, nullptr);
}

// Round 16
// 281.931 us; speedup vs baseline: 1.0418x; 1.0418x over previous
//
#include <hip/hip_runtime.h>
#include <hip/hip_bf16.h>
#include <math.h>

using bf16 = __hip_bfloat16;
typedef __bf16 bf16x8 __attribute__((ext_vector_type(8)));
typedef float f32x4 __attribute__((ext_vector_type(4)));

static constexpr int B_ = 2, T_ = 2048, D_ = 1024, H_ = 16, HD_ = 64, FH_ = 2752;
static constexpr int BT = B_ * T_;  // 4096

struct __align__(8)  bh4 { bf16 h[4]; };
struct __align__(16) bh8 { bf16 h[8]; };

#define DEV static __device__ __forceinline__

DEV float b2f(bf16 v) { return __bfloat162float(v); }
DEV bf16  f2b(float v) { return __float2bfloat16(v); }
DEV __bf16 f2bb(float f) { __hip_bfloat16 h = __float2bfloat16(f); return *reinterpret_cast<__bf16*>(&h); }
DEV float sigmoidf_(float x) { return 1.0f / (1.0f + __expf(-x)); }

DEV void load4f(const bf16* p, float* v) {
    bh4 t = *reinterpret_cast<const bh4*>(p);
#pragma unroll
    for (int i = 0; i < 4; ++i) v[i] = b2f(t.h[i]);
}
DEV void load4f(const float* p, float* v) {
    float4 t = *reinterpret_cast<const float4*>(p);
    v[0] = t.x; v[1] = t.y; v[2] = t.z; v[3] = t.w;
}
DEV void store4(float* p, const float* v) {
    float4 t; t.x = v[0]; t.y = v[1]; t.z = v[2]; t.w = v[3];
    *reinterpret_cast<float4*>(p) = t;
}
DEV float waveReduceSum(float v) {
#pragma unroll
    for (int m = 32; m; m >>= 1) v += __shfl_xor(v, m);
    return v;
}

// async global->LDS, 16B per lane; lds base wave-uniform, global addr per-lane
DEV void gl_lds16(const bf16* g, bf16* lds_base) {
    __builtin_amdgcn_global_load_lds(
        (const __attribute__((address_space(1))) void*)g,
        (__attribute__((address_space(3))) void*)lds_base, 16, 0, 0);
}

// ---------------- RoPE tables ----------------
__global__ __launch_bounds__(256) void k_rope_tables(float* __restrict__ cost, float* __restrict__ sint) {
    int idx = blockIdx.x * 256 + threadIdx.x;
    if (idx >= T_ * 32) return;
    int t = idx >> 5, j = idx & 31;
    float inv = powf(10000.0f, -(float)j * (1.0f / 32.0f));
    float f = (float)t * inv;
    cost[idx] = cosf(f);
    sint[idx] = sinf(f);
}

// ---------------- weight f32 -> bf16 (3 segments in one launch) ----------------
__global__ __launch_bounds__(256) void k_f2b3(const float* __restrict__ s0, const float* __restrict__ s1,
                                              const float* __restrict__ s2, bf16* __restrict__ out, int n8seg) {
    int i = blockIdx.x * 256 + threadIdx.x;
    if (i >= 3 * n8seg) return;
    int seg = i / n8seg, off = i - seg * n8seg;
    const float* src = (seg == 0) ? s0 : (seg == 1) ? s1 : s2;
    const float4* p = reinterpret_cast<const float4*>(src + (size_t)off * 8);
    float4 a = p[0], b = p[1];
    bh8 o;
    o.h[0] = f2b(a.x); o.h[1] = f2b(a.y); o.h[2] = f2b(a.z); o.h[3] = f2b(a.w);
    o.h[4] = f2b(b.x); o.h[5] = f2b(b.y); o.h[6] = f2b(b.z); o.h[7] = f2b(b.w);
    *reinterpret_cast<bh8*>(out + (size_t)i * 8) = o;
}

__global__ __launch_bounds__(256) void k_f2b(const float* __restrict__ in, bf16* __restrict__ out, int n8) {
    int i = blockIdx.x * 256 + threadIdx.x;
    if (i >= n8) return;
    const float4* p = reinterpret_cast<const float4*>(in + (size_t)i * 8);
    float4 a = p[0], b = p[1];
    bh8 o;
    o.h[0] = f2b(a.x); o.h[1] = f2b(a.y); o.h[2] = f2b(a.z); o.h[3] = f2b(a.w);
    o.h[4] = f2b(b.x); o.h[5] = f2b(b.y); o.h[6] = f2b(b.z); o.h[7] = f2b(b.w);
    *reinterpret_cast<bh8*>(out + (size_t)i * 8) = o;
}

// ---- w1/w3 -> 16-row-interleaved bf16 ----
__global__ __launch_bounds__(256) void k_f2b_pair(const float* __restrict__ w1, const float* __restrict__ w3,
                                                  bf16* __restrict__ outp, int n8tot) {
    int i = blockIdx.x * 256 + threadIdx.x;
    if (i >= n8tot) return;
    int r = i >> 7, c8 = i & 127;
    int sel = (r >> 4) & 1;
    int j = ((r >> 5) << 4) | (r & 15);
    const float* src = (sel ? w3 : w1) + (size_t)j * D_ + c8 * 8;
    float4 a = reinterpret_cast<const float4*>(src)[0];
    float4 b = reinterpret_cast<const float4*>(src)[1];
    bh8 o;
    o.h[0] = f2b(a.x); o.h[1] = f2b(a.y); o.h[2] = f2b(a.z); o.h[3] = f2b(a.w);
    o.h[4] = f2b(b.x); o.h[5] = f2b(b.y); o.h[6] = f2b(b.z); o.h[7] = f2b(b.w);
    *reinterpret_cast<bh8*>(outp + (size_t)r * D_ + c8 * 8) = o;
}

// ---------------- RMSNorm over D=1024 (f32 in, bf16 out) ----------------
__global__ __launch_bounds__(256) void k_rmsnorm(const float* __restrict__ x, const float* __restrict__ w,
                                                 bf16* __restrict__ out) {
    int row = blockIdx.x, tid = threadIdx.x;
    const float* xr = x + (size_t)row * D_;
    int base = tid * 4;
    float v[4];
    load4f(xr + base, v);
    float ss = v[0]*v[0] + v[1]*v[1] + v[2]*v[2] + v[3]*v[3];
    ss = waveReduceSum(ss);
    __shared__ float red[4];
    if ((tid & 63) == 0) red[tid >> 6] = ss;
    __syncthreads();
    ss = red[0] + red[1] + red[2] + red[3];
    float r = rsqrtf(ss * (1.0f / D_) + 1e-6f);
    float wv[4];
    load4f(w + base, wv);
    bh4 o;
#pragma unroll
    for (int i = 0; i < 4; ++i) o.h[i] = f2b(v[i] * r * wv[i]);
    *reinterpret_cast<bh4*>(out + (size_t)row * D_ + base) = o;
}

// ======== GEMM 256x128, BK=32, 512 threads (8 waves 4x2) — verified depth-2 vmcnt ring ========
// T4 counted-vmcnt: STAGE(t+2) after compute(t); wait vmcnt(3) (tile t done, t+1 in flight
// across the barrier). Raw s_barrier; sched_barrier pins; setprio around MFMA cluster.
// LDS[row][c] holds global chunk c ^ ((row>>1)&3) -> conflict-free ds_read_b128.
// EPI=0: C=acc. EPI=1: paired SwiGLU columns -> g[M][N/2].
template <int EPI>
__global__ __launch_bounds__(512) void k_gemm256(const bf16* __restrict__ A, const bf16* __restrict__ W,
                                                 bf16* __restrict__ C, int M, int N, int K) {
    __shared__ bf16 sA[2][256 * 32];
    __shared__ bf16 sB[2][128 * 32];
    int tid = threadIdx.x, lane = tid & 63, wid = tid >> 6;
    int m0 = blockIdx.x * 256, n0 = blockIdx.y * 128;
    int wr = wid >> 1, wc = wid & 1;
    int l16 = lane & 15, lg = lane >> 4;
    int srow = lane >> 2;
    int scol = ((lane & 3) ^ ((lane >> 3) & 3)) * 8;   // inverse-swizzled global chunk
    int rchunk = (lg ^ ((l16 >> 1) & 3)) * 8;          // swizzled fragment read chunk

    f32x4 acc[4][4] = {};

#define STAGE(buf, k0)                                                                   \
    {                                                                                    \
        _Pragma("unroll")                                                                \
        for (int c = 0; c < 2; ++c) {                                                    \
            int r0 = wid * 32 + c * 16;                                                  \
            gl_lds16(&A[(size_t)(m0 + r0 + srow) * K + (k0) + scol], &sA[buf][r0 * 32]); \
        }                                                                                \
        {                                                                                \
            int r0 = wid * 16;                                                           \
            gl_lds16(&W[(size_t)(n0 + r0 + srow) * K + (k0) + scol], &sB[buf][r0 * 32]); \
        }                                                                                \
    }

    int nk = K >> 5;
    STAGE(0, 0);
    if (nk > 1) STAGE(1, 32);
    for (int t = 0; t < nk; ++t) {
        if (t + 1 < nk) { asm volatile("s_waitcnt vmcnt(3)" ::: "memory"); }
        else            { asm volatile("s_waitcnt vmcnt(0)" ::: "memory"); }
        __builtin_amdgcn_s_barrier();
        __builtin_amdgcn_sched_barrier(0);
        int cur = t & 1;
        bf16x8 af[4], bfr[4];
#pragma unroll
        for (int m = 0; m < 4; ++m)
            af[m] = *reinterpret_cast<const bf16x8*>(&sA[cur][(wr * 64 + m * 16 + l16) * 32 + rchunk]);
#pragma unroll
        for (int n = 0; n < 4; ++n)
            bfr[n] = *reinterpret_cast<const bf16x8*>(&sB[cur][(wc * 64 + n * 16 + l16) * 32 + rchunk]);
        __builtin_amdgcn_s_setprio(1);
#pragma unroll
        for (int m = 0; m < 4; ++m)
#pragma unroll
            for (int n = 0; n < 4; ++n)
                acc[m][n] = __builtin_amdgcn_mfma_f32_16x16x32_bf16(af[m], bfr[n], acc[m][n], 0, 0, 0);
        __builtin_amdgcn_s_setprio(0);
        __builtin_amdgcn_sched_barrier(0);
        __builtin_amdgcn_s_barrier();
        if (t + 2 < nk) STAGE(cur, (t + 2) * 32);
    }
#undef STAGE

    int rbase = m0 + wr * 64;
    if (EPI == 1) {
        int Ng = N >> 1;
        int gbase = (n0 >> 1) + wc * 32;
#pragma unroll
        for (int m = 0; m < 4; ++m) {
#pragma unroll
            for (int n2 = 0; n2 < 2; ++n2) {
                int gcol = gbase + n2 * 16 + l16;
#pragma unroll
                for (int r = 0; r < 4; ++r) {
                    int row = rbase + m * 16 + lg * 4 + r;
                    float a1 = acc[m][n2 * 2][r];
                    float a3 = acc[m][n2 * 2 + 1][r];
                    C[(size_t)row * Ng + gcol] = f2b(a1 * sigmoidf_(a1) * a3);
                }
            }
        }
    } else {
        int cbase = n0 + wc * 64;
#pragma unroll
        for (int m = 0; m < 4; ++m) {
#pragma unroll
            for (int n = 0; n < 4; ++n) {
                int col = cbase + n * 16 + l16;
#pragma unroll
                for (int r = 0; r < 4; ++r) {
                    int row = rbase + m * 16 + lg * 4 + r;
                    C[(size_t)row * N + col] = f2b(acc[m][n][r]);
                }
            }
        }
    }
}

// ======== GEMM 128x64 (wo, w2), 256 threads (4 waves), depth-2 vmcnt ring ========
__global__ __launch_bounds__(256) void k_gemm64(const bf16* __restrict__ A, const bf16* __restrict__ W,
                                                bf16* __restrict__ C, int M, int N, int K) {
    __shared__ bf16 sA[2][128 * 32];
    __shared__ bf16 sB[2][64 * 32];
    int tid = threadIdx.x, lane = tid & 63, wid = tid >> 6;
    int m0 = blockIdx.x * 128, n0 = blockIdx.y * 64;
    int wr = wid;
    int l16 = lane & 15, lg = lane >> 4;
    int srow = lane >> 2;
    int scol = ((lane & 3) ^ ((lane >> 3) & 3)) * 8;
    int rchunk = (lg ^ ((l16 >> 1) & 3)) * 8;

    f32x4 acc[2][4] = {};

#define STAGE(buf, k0)                                                                   \
    {                                                                                    \
        _Pragma("unroll")                                                                \
        for (int c = 0; c < 2; ++c) {                                                    \
            int r0 = wid * 32 + c * 16;                                                  \
            gl_lds16(&A[(size_t)(m0 + r0 + srow) * K + (k0) + scol], &sA[buf][r0 * 32]); \
        }                                                                                \
        {                                                                                \
            int r0 = wid * 16;                                                           \
            gl_lds16(&W[(size_t)(n0 + r0 + srow) * K + (k0) + scol], &sB[buf][r0 * 32]); \
        }                                                                                \
    }

    int nk = K >> 5;
    STAGE(0, 0);
    if (nk > 1) STAGE(1, 32);
    for (int t = 0; t < nk; ++t) {
        if (t + 1 < nk) { asm volatile("s_waitcnt vmcnt(3)" ::: "memory"); }
        else            { asm volatile("s_waitcnt vmcnt(0)" ::: "memory"); }
        __builtin_amdgcn_s_barrier();
        __builtin_amdgcn_sched_barrier(0);
        int cur = t & 1;
        bf16x8 af[2], bfr[4];
#pragma unroll
        for (int m = 0; m < 2; ++m)
            af[m] = *reinterpret_cast<const bf16x8*>(&sA[cur][(wr * 32 + m * 16 + l16) * 32 + rchunk]);
#pragma unroll
        for (int n = 0; n < 4; ++n)
            bfr[n] = *reinterpret_cast<const bf16x8*>(&sB[cur][(n * 16 + l16) * 32 + rchunk]);
        __builtin_amdgcn_s_setprio(1);
#pragma unroll
        for (int m = 0; m < 2; ++m)
#pragma unroll
            for (int n = 0; n < 4; ++n)
                acc[m][n] = __builtin_amdgcn_mfma_f32_16x16x32_bf16(af[m], bfr[n], acc[m][n], 0, 0, 0);
        __builtin_amdgcn_s_setprio(0);
        __builtin_amdgcn_sched_barrier(0);
        __builtin_amdgcn_s_barrier();
        if (t + 2 < nk) STAGE(cur, (t + 2) * 32);
    }
#undef STAGE

    int rbase = m0 + wid * 32;
#pragma unroll
    for (int m = 0; m < 2; ++m) {
#pragma unroll
        for (int n = 0; n < 4; ++n) {
            int col = n0 + n * 16 + l16;
#pragma unroll
            for (int r = 0; r < 4; ++r) {
                int row = rbase + m * 16 + lg * 4 + r;
                C[(size_t)row * N + col] = f2b(acc[m][n][r]);
            }
        }
    }
}

// ---------------- per-head RMSNorm + RoPE ----------------
__global__ __launch_bounds__(256) void k_qk_norm_rope(const bf16* __restrict__ qin, const float* __restrict__ wn,
                                                      const float* __restrict__ cost, const float* __restrict__ sint,
                                                      bf16* __restrict__ qout, float scale, int ld, int off) {
    int tid = threadIdx.x;
    int g = blockIdx.x * 4 + (tid >> 6);
    int d = tid & 63;
    int h = g % H_, t = (g / H_) % T_, b = g / (H_ * T_);
    float v = b2f(qin[(size_t)(b * T_ + t) * ld + off + h * HD_ + d]);
    float ss = waveReduceSum(v * v);
    float r = rsqrtf(ss * (1.0f / HD_) + 1e-6f);
    float xn = v * r * wn[d];
    float p = __shfl_xor(xn, 32);
    float c = cost[t * 32 + (d & 31)], s = sint[t * 32 + (d & 31)];
    float o = (d < 32) ? (xn * c - p * s) : (xn * c + p * s);
    qout[((size_t)(b * H_ + h) * T_ + t) * HD_ + d] = f2b(o * scale);
}

// ---------------- V: strided (B*T, ld)+off -> (B,H,HD,T) ----------------
__global__ __launch_bounds__(256) void k_v_transpose(const bf16* __restrict__ vin, bf16* __restrict__ vt,
                                                     int ld, int off) {
    __shared__ bf16 tile[64][72];
    int tid = threadIdx.x;
    int bh = blockIdx.y;
    int t0 = blockIdx.x * 64;
    int b = bh >> 4, h = bh & 15;
#pragma unroll
    for (int i = 0; i < 16; ++i) {
        int lin = i * 256 + tid;
        int tl = lin >> 6, d = lin & 63;
        tile[tl][d] = vin[(size_t)(b * T_ + t0 + tl) * ld + off + h * HD_ + d];
    }
    __syncthreads();
#pragma unroll
    for (int i = 0; i < 16; ++i) {
        int lin = i * 256 + tid;
        int d = lin >> 6, tl = lin & 63;
        vt[((size_t)bh * HD_ + d) * T_ + t0 + tl] = tile[tl][d];
    }
}

// ---------------- Flash v3 + XCD swizzle + T13 defer-max (THR=8) ----------------
template <bool MASKED>
DEV void fa3_tile(const bf16* __restrict__ kl, const bf16* __restrict__ vl,
                  int l16, int lg, int qloc,
                  const bf16x8 qf0, const bf16x8 qf1,
                  f32x4* acc, float& m_r, float& l_r) {
    f32x4 s[8];
#pragma unroll
    for (int n = 0; n < 8; ++n) {
        int kv = n * 16 + l16;
        bf16x8 kf0 = *reinterpret_cast<const bf16x8*>(&kl[kv * 64 + (((lg ^ kv) & 7) << 3)]);
        bf16x8 kf1 = *reinterpret_cast<const bf16x8*>(&kl[kv * 64 + ((((4 + lg) ^ kv) & 7) << 3)]);
        f32x4 t = {};
        t = __builtin_amdgcn_mfma_f32_16x16x32_bf16(kf0, qf0, t, 0, 0, 0);
        t = __builtin_amdgcn_mfma_f32_16x16x32_bf16(kf1, qf1, t, 0, 0, 0);
        s[n] = t;
    }
    if (MASKED) {
#pragma unroll
        for (int n = 0; n < 8; ++n)
#pragma unroll
            for (int r = 0; r < 4; ++r)
                if (n * 16 + lg * 4 + r > qloc) s[n][r] = -INFINITY;
    }
    float mx = -INFINITY;
#pragma unroll
    for (int n = 0; n < 8; ++n)
#pragma unroll
        for (int r = 0; r < 4; ++r) mx = fmaxf(mx, s[n][r]);
    mx = fmaxf(mx, __shfl_xor(mx, 16));
    mx = fmaxf(mx, __shfl_xor(mx, 32));
    if (!__all(mx - m_r <= 8.0f)) {
        float mnew = fmaxf(m_r, mx);
        float corr = __expf(m_r - mnew);
        m_r = mnew;
        l_r *= corr;
#pragma unroll
        for (int np = 0; np < 4; ++np) acc[np] = acc[np] * corr;
    }
    float ps = 0.0f;
#pragma unroll
    for (int n = 0; n < 8; ++n)
#pragma unroll
        for (int r = 0; r < 4; ++r) {
            float e = __expf(s[n][r] - m_r);
            s[n][r] = e;
            ps += e;
        }
    l_r += ps;

    bf16x8 pb[4];
#pragma unroll
    for (int n2 = 0; n2 < 4; ++n2)
#pragma unroll
        for (int j = 0; j < 8; ++j)
            pb[n2][j] = f2bb(s[2 * n2 + (j >> 2)][j & 3]);

    int d15 = l16;
    int eoff = (lg & 1) * 4;
#pragma unroll
    for (int n2 = 0; n2 < 4; ++n2) {
        int c0 = (n2 * 4 + (lg >> 1));
        int c1 = c0 + 2;
#pragma unroll
        for (int np = 0; np < 4; ++np) {
            int d = np * 16 + l16;
            union { bf16x8 v; bh4 q[2]; } u;
            u.q[0] = *reinterpret_cast<const bh4*>(&vl[d * 128 + ((c0 ^ d15) << 3) + eoff]);
            u.q[1] = *reinterpret_cast<const bh4*>(&vl[d * 128 + ((c1 ^ d15) << 3) + eoff]);
            acc[np] = __builtin_amdgcn_mfma_f32_16x16x32_bf16(u.v, pb[n2], acc[np], 0, 0, 0);
        }
    }
}

__global__ __launch_bounds__(256) void k_flash(const bf16* __restrict__ Q, const bf16* __restrict__ Kk,
                                               const bf16* __restrict__ Vt, bf16* __restrict__ Out) {
    __shared__ bf16 kl[128 * 64];
    __shared__ bf16 vl[64 * 128];
    int tid = threadIdx.x, lane = tid & 63, w = tid >> 6;
    int l16 = lane & 15, lg = lane >> 4;
    int L = blockIdx.x;
    int xcd = L & 7, m = L >> 3;
    int bh = xcd * 4 + (m & 3);
    int qi = (T_ / 128 - 1) - (m >> 2);
    int q0 = qi * 128;
    int b = bh >> 4, h = bh & 15;
    const bf16* qb = Q + (size_t)bh * T_ * HD_;
    const bf16* kb = Kk + (size_t)bh * T_ * HD_;
    const bf16* vb = Vt + (size_t)bh * HD_ * T_;

    bf16x8 qfr[2][2];
#pragma unroll
    for (int f = 0; f < 2; ++f) {
        int qrow = q0 + w * 32 + f * 16 + l16;
        const bf16* qp = qb + (size_t)qrow * HD_ + lg * 8;
        qfr[f][0] = *reinterpret_cast<const bf16x8*>(qp);
        qfr[f][1] = *reinterpret_cast<const bf16x8*>(qp + 32);
    }
    f32x4 acc[2][4] = {};
    float m_r[2] = {-INFINITY, -INFINITY};
    float l_r[2] = {0.0f, 0.0f};

    for (int kv0 = 0; kv0 <= q0; kv0 += 128) {
        __syncthreads();
#pragma unroll
        for (int i = 0; i < 4; ++i) {
            int idx = i * 256 + tid;
            int kv = idx >> 3, c = idx & 7;
            *reinterpret_cast<bh8*>(&kl[kv * 64 + (((c ^ kv) & 7) << 3)]) =
                *reinterpret_cast<const bh8*>(&kb[(size_t)(kv0 + kv) * HD_ + c * 8]);
        }
#pragma unroll
        for (int i = 0; i < 4; ++i) {
            int idx = i * 256 + tid;
            int d = idx >> 4, c = idx & 15;
            *reinterpret_cast<bh8*>(&vl[d * 128 + (((c ^ d) & 15) << 3)]) =
                *reinterpret_cast<const bh8*>(&vb[(size_t)d * T_ + kv0 + c * 8]);
        }
        __syncthreads();
        if (kv0 == q0) {
#pragma unroll
            for (int f = 0; f < 2; ++f)
                fa3_tile<true>(kl, vl, l16, lg, w * 32 + f * 16 + l16,
                               qfr[f][0], qfr[f][1], acc[f], m_r[f], l_r[f]);
        } else {
#pragma unroll
            for (int f = 0; f < 2; ++f)
                fa3_tile<false>(kl, vl, l16, lg, 0,
                                qfr[f][0], qfr[f][1], acc[f], m_r[f], l_r[f]);
        }
    }
#pragma unroll
    for (int f = 0; f < 2; ++f) {
        float lt = l_r[f];
        lt += __shfl_xor(lt, 16);
        lt += __shfl_xor(lt, 32);
        float inv = 1.0f / lt;
        int qrow = q0 + w * 32 + f * 16 + l16;
#pragma unroll
        for (int np = 0; np < 4; ++np) {
            bh4 o;
#pragma unroll
            for (int r = 0; r < 4; ++r) o.h[r] = f2b(acc[f][np][r] * inv);
            *reinterpret_cast<bh4*>(&Out[(size_t)(b * T_ + qrow) * D_ + h * HD_ + np * 16 + lg * 4]) = o;
        }
    }
}

// ---------------- delta_res (optionally fused with following RMSNorm) ----------------
template <int WRITE_XM>
__global__ __launch_bounds__(256) void k_delta_res(const float* __restrict__ x, const bf16* __restrict__ h,
                                                   const float* __restrict__ gn_w, const float* __restrict__ g_w,
                                                   const float* __restrict__ g_b, const float* __restrict__ wv_w,
                                                   float* __restrict__ out,
                                                   bf16* __restrict__ xm_out, const float* __restrict__ mlp_w) {
    int row = blockIdx.x, tid = threadIdx.x;
    int base = tid * 4;
    float xv[4], hv[4], gnv[4], gwv[4], wvv[4];
    load4f(x + (size_t)row * D_ + base, xv);
    load4f(h + (size_t)row * D_ + base, hv);
    load4f(gn_w + base, gnv);
    load4f(g_w + base, gwv);
    load4f(wv_w + base, wvv);
    float s_h2 = 0, s_x2 = 0, s_xg = 0, s_xv = 0, s_hx = 0;
#pragma unroll
    for (int i = 0; i < 4; ++i) {
        s_h2 += hv[i] * hv[i];
        s_x2 += xv[i] * xv[i];
        s_xg += xv[i] * gnv[i] * gwv[i];
        s_xv += xv[i] * wvv[i];
        s_hx += hv[i] * xv[i];
    }
    s_h2 = waveReduceSum(s_h2); s_x2 = waveReduceSum(s_x2); s_xg = waveReduceSum(s_xg);
    s_xv = waveReduceSum(s_xv); s_hx = waveReduceSum(s_hx);
    __shared__ float red[4][5];
    int wid = tid >> 6;
    if ((tid & 63) == 0) {
        red[wid][0] = s_h2; red[wid][1] = s_x2; red[wid][2] = s_xg;
        red[wid][3] = s_xv; red[wid][4] = s_hx;
    }
    __syncthreads();
    s_h2 = red[0][0] + red[1][0] + red[2][0] + red[3][0];
    s_x2 = red[0][1] + red[1][1] + red[2][1] + red[3][1];
    s_xg = red[0][2] + red[1][2] + red[2][2] + red[3][2];
    s_xv = red[0][3] + red[1][3] + red[2][3] + red[3][3];
    s_hx = red[0][4] + red[1][4] + red[2][4] + red[3][4];

    float r = rsqrtf(s_x2 * (1.0f / D_) + 1e-6f);
    float logit = r * s_xg + g_b[0];
    float beta = 2.0f * sigmoidf_(logit);
    float vsig = sigmoidf_(s_xv);
    float nrm = sqrtf(s_h2);
    float ks = (1.0f / 32.0f) / fmaxf(nrm, 1e-6f);
    float coef = beta * (vsig - ks * s_hx) * ks;
    float o[4];
#pragma unroll
    for (int i = 0; i < 4; ++i) o[i] = xv[i] + coef * hv[i];
    store4(out + (size_t)row * D_ + base, o);

    if (WRITE_XM) {
        float s2 = o[0]*o[0] + o[1]*o[1] + o[2]*o[2] + o[3]*o[3];
        s2 = waveReduceSum(s2);
        __shared__ float red2[4];
        __syncthreads();
        if ((tid & 63) == 0) red2[wid] = s2;
        __syncthreads();
        s2 = red2[0] + red2[1] + red2[2] + red2[3];
        float rr = rsqrtf(s2 * (1.0f / D_) + 1e-6f);
        float mw[4];
        load4f(mlp_w + base, mw);
        bh4 ob;
#pragma unroll
        for (int i = 0; i < 4; ++i) ob.h[i] = f2b(o[i] * rr * mw[i]);
        *reinterpret_cast<bh4*>(xm_out + (size_t)row * D_ + base) = ob;
    }
}

extern "C" void kernel_launch(void* const* d_in, const int* in_sizes, int n_in,
                              void* d_out, int out_size, void* d_ws, size_t ws_size,
                              hipStream_t stream) {
    const float* x       = (const float*)d_in[0];
    const float* wq      = (const float*)d_in[1];
    const float* wk      = (const float*)d_in[2];
    const float* wv      = (const float*)d_in[3];
    const float* wo      = (const float*)d_in[4];
    const float* qn_w    = (const float*)d_in[5];
    const float* kn_w    = (const float*)d_in[6];
    const float* attn_nw = (const float*)d_in[7];
    const float* g1_nw   = (const float*)d_in[8];
    const float* g1_w    = (const float*)d_in[9];
    const float* g1_b    = (const float*)d_in[10];
    const float* wv1     = (const float*)d_in[11];
    const float* mlp_nw  = (const float*)d_in[12];
    const float* w1      = (const float*)d_in[13];
    const float* w2      = (const float*)d_in[14];
    const float* w3      = (const float*)d_in[15];
    const float* g2_nw   = (const float*)d_in[16];
    const float* g2_w    = (const float*)d_in[17];
    const float* g2_b    = (const float*)d_in[18];
    const float* wv2     = (const float*)d_in[19];
    float* out = (float*)d_out;

    char* ws = (char*)d_ws;
    const size_t KB = 1024;
    const size_t MB = 1024 * 1024;
    float* cost = (float*)(ws);                        // 256 KB
    float* sint = (float*)(ws + 256 * KB);             // 256 KB
    bf16* XC = (bf16*)(ws + 512 * KB);                 // 8MB: xc -> wo_bf16 -> xm -> hmlp
    bf16* Bb = (bf16*)(ws + 512 * KB + 8  * MB);       // Bb..Db 24MB: qkv -> attn_out -> wpair/w2b
    bf16* Cb = (bf16*)(ws + 512 * KB + 16 * MB);       // 8MB: h_attn
    bf16* Db = (bf16*)(ws + 512 * KB + 24 * MB);       // 8MB: w2 bf16
    bf16* Eb = (bf16*)(ws + 512 * KB + 32 * MB);       // Eb..Gb 24MB: wqkv -> Qr/Kr/Vt -> g
    bf16* Fb = (bf16*)(ws + 512 * KB + 40 * MB);
    bf16* Gb = (bf16*)(ws + 512 * KB + 48 * MB);
    float* x1 = (float*)(ws + 512 * KB + 56 * MB);     // 16MB f32

    bf16* wqkv = Eb;
    bf16* qkv  = Bb;
    bf16* wbo  = XC;
    bf16* attn_out = Bb;
    bf16* wpair = Bb;
    bf16* w2b  = Db;
    bf16* g    = Eb;
    bf16* hmlp = XC;

    const int nDD = D_ * D_ / 8, nFD = FH_ * D_ / 8;
    dim3 blk(256);

    k_rope_tables<<<dim3((T_ * 32) / 256), blk, 0, stream>>>(cost, sint);

    k_rmsnorm<<<dim3(BT), blk, 0, stream>>>(x, attn_nw, XC);
    // wq|wk|wv -> contiguous bf16 [3072][1024] in one launch
    k_f2b3<<<dim3((3 * nDD + 255) / 256), blk, 0, stream>>>(wq, wk, wv, wqkv, nDD);

    // fused QKV GEMM: 256x128 tiles, grid (16, 24)
    k_gemm256<0><<<dim3(16, 24), dim3(512), 0, stream>>>(XC, wqkv, qkv, BT, 3 * D_, D_);

    k_qk_norm_rope<<<dim3(BT * H_ / 4), blk, 0, stream>>>(qkv, qn_w, cost, sint, Eb, 0.125f, 3 * D_, 0);
    k_qk_norm_rope<<<dim3(BT * H_ / 4), blk, 0, stream>>>(qkv, kn_w, cost, sint, Fb, 1.0f, 3 * D_, D_);
    k_v_transpose<<<dim3(T_ / 64, B_ * H_), blk, 0, stream>>>(qkv, Gb, 3 * D_, 2 * D_);

    k_f2b<<<dim3((nDD + 255) / 256), blk, 0, stream>>>(wo, wbo, nDD);
    k_flash<<<dim3((T_ / 128) * B_ * H_), blk, 0, stream>>>(Eb, Fb, Gb, attn_out);

    // h_attn = attn_out @ wo^T : 128x64 tiles, grid (32, 16)
    k_gemm64<<<dim3(32, 16), blk, 0, stream>>>(attn_out, wbo, Cb, BT, D_, D_);

    // x1 = delta_res(x, h_attn)  (+ fused xm = rmsnorm(x1, mlp_nw) -> XC)
    k_delta_res<1><<<dim3(BT), blk, 0, stream>>>(x, Cb, g1_nw, g1_w, g1_b, wv1, x1, XC, mlp_nw);

    k_f2b_pair<<<dim3((2 * nFD + 255) / 256), blk, 0, stream>>>(w1, w3, wpair, 2 * nFD);
    k_f2b<<<dim3((nFD + 255) / 256), blk, 0, stream>>>(w2, w2b, nFD);

    // g = silu(xm@w1^T)*(xm@w3^T): 256x128 tiles, grid (16, 43)
    k_gemm256<1><<<dim3(16, 43), dim3(512), 0, stream>>>(XC, wpair, g, BT, 2 * FH_, D_);

    // h_mlp = g @ w2^T : 128x64, grid (32, 16)
    k_gemm64<<<dim3(32, 16), blk, 0, stream>>>(g, w2b, hmlp, BT, D_, FH_);

    // out = delta_res(x1, h_mlp)
    k_delta_res<0><<<dim3(BT), blk, 0, stream>>>(x1, hmlp, g2_nw, g2_w, g2_b, wv2, out, nullptr, nullptr);
}

// Round 17
// 278.111 us; speedup vs baseline: 1.0561x; 1.0137x over previous
//
#include <hip/hip_runtime.h>
#include <hip/hip_bf16.h>
#include <math.h>

using bf16 = __hip_bfloat16;
typedef __bf16 bf16x8 __attribute__((ext_vector_type(8)));
typedef float f32x4 __attribute__((ext_vector_type(4)));

static constexpr int B_ = 2, T_ = 2048, D_ = 1024, H_ = 16, HD_ = 64, FH_ = 2752;
static constexpr int BT = B_ * T_;  // 4096

struct __align__(8)  bh4 { bf16 h[4]; };
struct __align__(16) bh8 { bf16 h[8]; };

#define DEV static __device__ __forceinline__

DEV float b2f(bf16 v) { return __bfloat162float(v); }
DEV bf16  f2b(float v) { return __float2bfloat16(v); }
DEV __bf16 f2bb(float f) { __hip_bfloat16 h = __float2bfloat16(f); return *reinterpret_cast<__bf16*>(&h); }
DEV float sigmoidf_(float x) { return 1.0f / (1.0f + __expf(-x)); }

DEV void load4f(const bf16* p, float* v) {
    bh4 t = *reinterpret_cast<const bh4*>(p);
#pragma unroll
    for (int i = 0; i < 4; ++i) v[i] = b2f(t.h[i]);
}
DEV void load4f(const float* p, float* v) {
    float4 t = *reinterpret_cast<const float4*>(p);
    v[0] = t.x; v[1] = t.y; v[2] = t.z; v[3] = t.w;
}
DEV void store4(float* p, const float* v) {
    float4 t; t.x = v[0]; t.y = v[1]; t.z = v[2]; t.w = v[3];
    *reinterpret_cast<float4*>(p) = t;
}
DEV float waveReduceSum(float v) {
#pragma unroll
    for (int m = 32; m; m >>= 1) v += __shfl_xor(v, m);
    return v;
}

// async global->LDS, 16B per lane; lds base wave-uniform, global addr per-lane
DEV void gl_lds16(const bf16* g, bf16* lds_base) {
    __builtin_amdgcn_global_load_lds(
        (const __attribute__((address_space(1))) void*)g,
        (__attribute__((address_space(3))) void*)lds_base, 16, 0, 0);
}

// ---------------- RoPE tables ----------------
__global__ __launch_bounds__(256) void k_rope_tables(float* __restrict__ cost, float* __restrict__ sint) {
    int idx = blockIdx.x * 256 + threadIdx.x;
    if (idx >= T_ * 32) return;
    int t = idx >> 5, j = idx & 31;
    float inv = powf(10000.0f, -(float)j * (1.0f / 32.0f));
    float f = (float)t * inv;
    cost[idx] = cosf(f);
    sint[idx] = sinf(f);
}

// ---------------- weight f32 -> bf16 (3 segments in one launch) ----------------
__global__ __launch_bounds__(256) void k_f2b3(const float* __restrict__ s0, const float* __restrict__ s1,
                                              const float* __restrict__ s2, bf16* __restrict__ out, int n8seg) {
    int i = blockIdx.x * 256 + threadIdx.x;
    if (i >= 3 * n8seg) return;
    int seg = i / n8seg, off = i - seg * n8seg;
    const float* src = (seg == 0) ? s0 : (seg == 1) ? s1 : s2;
    const float4* p = reinterpret_cast<const float4*>(src + (size_t)off * 8);
    float4 a = p[0], b = p[1];
    bh8 o;
    o.h[0] = f2b(a.x); o.h[1] = f2b(a.y); o.h[2] = f2b(a.z); o.h[3] = f2b(a.w);
    o.h[4] = f2b(b.x); o.h[5] = f2b(b.y); o.h[6] = f2b(b.z); o.h[7] = f2b(b.w);
    *reinterpret_cast<bh8*>(out + (size_t)i * 8) = o;
}

__global__ __launch_bounds__(256) void k_f2b(const float* __restrict__ in, bf16* __restrict__ out, int n8) {
    int i = blockIdx.x * 256 + threadIdx.x;
    if (i >= n8) return;
    const float4* p = reinterpret_cast<const float4*>(in + (size_t)i * 8);
    float4 a = p[0], b = p[1];
    bh8 o;
    o.h[0] = f2b(a.x); o.h[1] = f2b(a.y); o.h[2] = f2b(a.z); o.h[3] = f2b(a.w);
    o.h[4] = f2b(b.x); o.h[5] = f2b(b.y); o.h[6] = f2b(b.z); o.h[7] = f2b(b.w);
    *reinterpret_cast<bh8*>(out + (size_t)i * 8) = o;
}

// ---- merged FFN weight conversion: w1/w3 16-row-interleaved (seg 0) + w2 plain (seg 1) ----
__global__ __launch_bounds__(256) void k_f2b_ffn(const float* __restrict__ w1, const float* __restrict__ w3,
                                                 const float* __restrict__ w2,
                                                 bf16* __restrict__ outp, bf16* __restrict__ outw2, int nFD) {
    int i = blockIdx.x * 256 + threadIdx.x;
    int npair = 2 * nFD;
    if (i < npair) {
        int r = i >> 7, c8 = i & 127;
        int sel = (r >> 4) & 1;
        int j = ((r >> 5) << 4) | (r & 15);
        const float* src = (sel ? w3 : w1) + (size_t)j * D_ + c8 * 8;
        float4 a = reinterpret_cast<const float4*>(src)[0];
        float4 b = reinterpret_cast<const float4*>(src)[1];
        bh8 o;
        o.h[0] = f2b(a.x); o.h[1] = f2b(a.y); o.h[2] = f2b(a.z); o.h[3] = f2b(a.w);
        o.h[4] = f2b(b.x); o.h[5] = f2b(b.y); o.h[6] = f2b(b.z); o.h[7] = f2b(b.w);
        *reinterpret_cast<bh8*>(outp + (size_t)r * D_ + c8 * 8) = o;
    } else if (i < npair + nFD) {
        int off = i - npair;
        const float4* p = reinterpret_cast<const float4*>(w2 + (size_t)off * 8);
        float4 a = p[0], b = p[1];
        bh8 o;
        o.h[0] = f2b(a.x); o.h[1] = f2b(a.y); o.h[2] = f2b(a.z); o.h[3] = f2b(a.w);
        o.h[4] = f2b(b.x); o.h[5] = f2b(b.y); o.h[6] = f2b(b.z); o.h[7] = f2b(b.w);
        *reinterpret_cast<bh8*>(outw2 + (size_t)off * 8) = o;
    }
}

// ---------------- RMSNorm over D=1024 (f32 in, bf16 out) ----------------
__global__ __launch_bounds__(256) void k_rmsnorm(const float* __restrict__ x, const float* __restrict__ w,
                                                 bf16* __restrict__ out) {
    int row = blockIdx.x, tid = threadIdx.x;
    const float* xr = x + (size_t)row * D_;
    int base = tid * 4;
    float v[4];
    load4f(xr + base, v);
    float ss = v[0]*v[0] + v[1]*v[1] + v[2]*v[2] + v[3]*v[3];
    ss = waveReduceSum(ss);
    __shared__ float red[4];
    if ((tid & 63) == 0) red[tid >> 6] = ss;
    __syncthreads();
    ss = red[0] + red[1] + red[2] + red[3];
    float r = rsqrtf(ss * (1.0f / D_) + 1e-6f);
    float wv[4];
    load4f(w + base, wv);
    bh4 o;
#pragma unroll
    for (int i = 0; i < 4; ++i) o.h[i] = f2b(v[i] * r * wv[i]);
    *reinterpret_cast<bh4*>(out + (size_t)row * D_ + base) = o;
}

// ======== GEMM 256x128, BK=32, 512 threads (8 waves 4x2) — verified depth-2 vmcnt ring ========
template <int EPI>
__global__ __launch_bounds__(512) void k_gemm256(const bf16* __restrict__ A, const bf16* __restrict__ W,
                                                 bf16* __restrict__ C, int M, int N, int K) {
    __shared__ bf16 sA[2][256 * 32];
    __shared__ bf16 sB[2][128 * 32];
    int tid = threadIdx.x, lane = tid & 63, wid = tid >> 6;
    int m0 = blockIdx.x * 256, n0 = blockIdx.y * 128;
    int wr = wid >> 1, wc = wid & 1;
    int l16 = lane & 15, lg = lane >> 4;
    int srow = lane >> 2;
    int scol = ((lane & 3) ^ ((lane >> 3) & 3)) * 8;
    int rchunk = (lg ^ ((l16 >> 1) & 3)) * 8;

    f32x4 acc[4][4] = {};

#define STAGE(buf, k0)                                                                   \
    {                                                                                    \
        _Pragma("unroll")                                                                \
        for (int c = 0; c < 2; ++c) {                                                    \
            int r0 = wid * 32 + c * 16;                                                  \
            gl_lds16(&A[(size_t)(m0 + r0 + srow) * K + (k0) + scol], &sA[buf][r0 * 32]); \
        }                                                                                \
        {                                                                                \
            int r0 = wid * 16;                                                           \
            gl_lds16(&W[(size_t)(n0 + r0 + srow) * K + (k0) + scol], &sB[buf][r0 * 32]); \
        }                                                                                \
    }

    int nk = K >> 5;
    STAGE(0, 0);
    if (nk > 1) STAGE(1, 32);
    for (int t = 0; t < nk; ++t) {
        if (t + 1 < nk) { asm volatile("s_waitcnt vmcnt(3)" ::: "memory"); }
        else            { asm volatile("s_waitcnt vmcnt(0)" ::: "memory"); }
        __builtin_amdgcn_s_barrier();
        __builtin_amdgcn_sched_barrier(0);
        int cur = t & 1;
        bf16x8 af[4], bfr[4];
#pragma unroll
        for (int m = 0; m < 4; ++m)
            af[m] = *reinterpret_cast<const bf16x8*>(&sA[cur][(wr * 64 + m * 16 + l16) * 32 + rchunk]);
#pragma unroll
        for (int n = 0; n < 4; ++n)
            bfr[n] = *reinterpret_cast<const bf16x8*>(&sB[cur][(wc * 64 + n * 16 + l16) * 32 + rchunk]);
        __builtin_amdgcn_s_setprio(1);
#pragma unroll
        for (int m = 0; m < 4; ++m)
#pragma unroll
            for (int n = 0; n < 4; ++n)
                acc[m][n] = __builtin_amdgcn_mfma_f32_16x16x32_bf16(af[m], bfr[n], acc[m][n], 0, 0, 0);
        __builtin_amdgcn_s_setprio(0);
        __builtin_amdgcn_sched_barrier(0);
        __builtin_amdgcn_s_barrier();
        if (t + 2 < nk) STAGE(cur, (t + 2) * 32);
    }
#undef STAGE

    int rbase = m0 + wr * 64;
    if (EPI == 1) {
        int Ng = N >> 1;
        int gbase = (n0 >> 1) + wc * 32;
#pragma unroll
        for (int m = 0; m < 4; ++m) {
#pragma unroll
            for (int n2 = 0; n2 < 2; ++n2) {
                int gcol = gbase + n2 * 16 + l16;
#pragma unroll
                for (int r = 0; r < 4; ++r) {
                    int row = rbase + m * 16 + lg * 4 + r;
                    float a1 = acc[m][n2 * 2][r];
                    float a3 = acc[m][n2 * 2 + 1][r];
                    C[(size_t)row * Ng + gcol] = f2b(a1 * sigmoidf_(a1) * a3);
                }
            }
        }
    } else {
        int cbase = n0 + wc * 64;
#pragma unroll
        for (int m = 0; m < 4; ++m) {
#pragma unroll
            for (int n = 0; n < 4; ++n) {
                int col = cbase + n * 16 + l16;
#pragma unroll
                for (int r = 0; r < 4; ++r) {
                    int row = rbase + m * 16 + lg * 4 + r;
                    C[(size_t)row * N + col] = f2b(acc[m][n][r]);
                }
            }
        }
    }
}

// ======== GEMM 128x64 (wo, w2), 256 threads (4 waves), depth-2 vmcnt ring ========
__global__ __launch_bounds__(256) void k_gemm64(const bf16* __restrict__ A, const bf16* __restrict__ W,
                                                bf16* __restrict__ C, int M, int N, int K) {
    __shared__ bf16 sA[2][128 * 32];
    __shared__ bf16 sB[2][64 * 32];
    int tid = threadIdx.x, lane = tid & 63, wid = tid >> 6;
    int m0 = blockIdx.x * 128, n0 = blockIdx.y * 64;
    int wr = wid;
    int l16 = lane & 15, lg = lane >> 4;
    int srow = lane >> 2;
    int scol = ((lane & 3) ^ ((lane >> 3) & 3)) * 8;
    int rchunk = (lg ^ ((l16 >> 1) & 3)) * 8;

    f32x4 acc[2][4] = {};

#define STAGE(buf, k0)                                                                   \
    {                                                                                    \
        _Pragma("unroll")                                                                \
        for (int c = 0; c < 2; ++c) {                                                    \
            int r0 = wid * 32 + c * 16;                                                  \
            gl_lds16(&A[(size_t)(m0 + r0 + srow) * K + (k0) + scol], &sA[buf][r0 * 32]); \
        }                                                                                \
        {                                                                                \
            int r0 = wid * 16;                                                           \
            gl_lds16(&W[(size_t)(n0 + r0 + srow) * K + (k0) + scol], &sB[buf][r0 * 32]); \
        }                                                                                \
    }

    int nk = K >> 5;
    STAGE(0, 0);
    if (nk > 1) STAGE(1, 32);
    for (int t = 0; t < nk; ++t) {
        if (t + 1 < nk) { asm volatile("s_waitcnt vmcnt(3)" ::: "memory"); }
        else            { asm volatile("s_waitcnt vmcnt(0)" ::: "memory"); }
        __builtin_amdgcn_s_barrier();
        __builtin_amdgcn_sched_barrier(0);
        int cur = t & 1;
        bf16x8 af[2], bfr[4];
#pragma unroll
        for (int m = 0; m < 2; ++m)
            af[m] = *reinterpret_cast<const bf16x8*>(&sA[cur][(wr * 32 + m * 16 + l16) * 32 + rchunk]);
#pragma unroll
        for (int n = 0; n < 4; ++n)
            bfr[n] = *reinterpret_cast<const bf16x8*>(&sB[cur][(n * 16 + l16) * 32 + rchunk]);
        __builtin_amdgcn_s_setprio(1);
#pragma unroll
        for (int m = 0; m < 2; ++m)
#pragma unroll
            for (int n = 0; n < 4; ++n)
                acc[m][n] = __builtin_amdgcn_mfma_f32_16x16x32_bf16(af[m], bfr[n], acc[m][n], 0, 0, 0);
        __builtin_amdgcn_s_setprio(0);
        __builtin_amdgcn_sched_barrier(0);
        __builtin_amdgcn_s_barrier();
        if (t + 2 < nk) STAGE(cur, (t + 2) * 32);
    }
#undef STAGE

    int rbase = m0 + wid * 32;
#pragma unroll
    for (int m = 0; m < 2; ++m) {
#pragma unroll
        for (int n = 0; n < 4; ++n) {
            int col = n0 + n * 16 + l16;
#pragma unroll
            for (int r = 0; r < 4; ++r) {
                int row = rbase + m * 16 + lg * 4 + r;
                C[(size_t)row * N + col] = f2b(acc[m][n][r]);
            }
        }
    }
}

// ---------------- per-head RMSNorm + RoPE: Q and K in ONE launch ----------------
__global__ __launch_bounds__(256) void k_qk_norm_rope2(const bf16* __restrict__ qkv,
                                                       const float* __restrict__ qn_w, const float* __restrict__ kn_w,
                                                       const float* __restrict__ cost, const float* __restrict__ sint,
                                                       bf16* __restrict__ qout, bf16* __restrict__ kout, int nbHalf) {
    int tid = threadIdx.x;
    int bx = blockIdx.x;
    int isK = (bx >= nbHalf);
    int g = (isK ? bx - nbHalf : bx) * 4 + (tid >> 6);
    int d = tid & 63;
    int h = g % H_, t = (g / H_) % T_, b = g / (H_ * T_);
    const float* wn = isK ? kn_w : qn_w;
    bf16* qo = isK ? kout : qout;
    float scale = isK ? 1.0f : 0.125f;
    int off = isK ? D_ : 0;
    float v = b2f(qkv[(size_t)(b * T_ + t) * (3 * D_) + off + h * HD_ + d]);
    float ss = waveReduceSum(v * v);
    float r = rsqrtf(ss * (1.0f / HD_) + 1e-6f);
    float xn = v * r * wn[d];
    float p = __shfl_xor(xn, 32);
    float c = cost[t * 32 + (d & 31)], s = sint[t * 32 + (d & 31)];
    float o = (d < 32) ? (xn * c - p * s) : (xn * c + p * s);
    qo[((size_t)(b * H_ + h) * T_ + t) * HD_ + d] = f2b(o * scale);
}

// ---------------- V: strided (B*T, ld)+off -> (B,H,HD,T) ----------------
__global__ __launch_bounds__(256) void k_v_transpose(const bf16* __restrict__ vin, bf16* __restrict__ vt,
                                                     int ld, int off) {
    __shared__ bf16 tile[64][72];
    int tid = threadIdx.x;
    int bh = blockIdx.y;
    int t0 = blockIdx.x * 64;
    int b = bh >> 4, h = bh & 15;
#pragma unroll
    for (int i = 0; i < 16; ++i) {
        int lin = i * 256 + tid;
        int tl = lin >> 6, d = lin & 63;
        tile[tl][d] = vin[(size_t)(b * T_ + t0 + tl) * ld + off + h * HD_ + d];
    }
    __syncthreads();
#pragma unroll
    for (int i = 0; i < 16; ++i) {
        int lin = i * 256 + tid;
        int d = lin >> 6, tl = lin & 63;
        vt[((size_t)bh * HD_ + d) * T_ + t0 + tl] = tile[tl][d];
    }
}

// ---------------- Flash v3 + XCD swizzle + T13 defer-max (THR=8) ----------------
template <bool MASKED>
DEV void fa3_tile(const bf16* __restrict__ kl, const bf16* __restrict__ vl,
                  int l16, int lg, int qloc,
                  const bf16x8 qf0, const bf16x8 qf1,
                  f32x4* acc, float& m_r, float& l_r) {
    f32x4 s[8];
#pragma unroll
    for (int n = 0; n < 8; ++n) {
        int kv = n * 16 + l16;
        bf16x8 kf0 = *reinterpret_cast<const bf16x8*>(&kl[kv * 64 + (((lg ^ kv) & 7) << 3)]);
        bf16x8 kf1 = *reinterpret_cast<const bf16x8*>(&kl[kv * 64 + ((((4 + lg) ^ kv) & 7) << 3)]);
        f32x4 t = {};
        t = __builtin_amdgcn_mfma_f32_16x16x32_bf16(kf0, qf0, t, 0, 0, 0);
        t = __builtin_amdgcn_mfma_f32_16x16x32_bf16(kf1, qf1, t, 0, 0, 0);
        s[n] = t;
    }
    if (MASKED) {
#pragma unroll
        for (int n = 0; n < 8; ++n)
#pragma unroll
            for (int r = 0; r < 4; ++r)
                if (n * 16 + lg * 4 + r > qloc) s[n][r] = -INFINITY;
    }
    float mx = -INFINITY;
#pragma unroll
    for (int n = 0; n < 8; ++n)
#pragma unroll
        for (int r = 0; r < 4; ++r) mx = fmaxf(mx, s[n][r]);
    mx = fmaxf(mx, __shfl_xor(mx, 16));
    mx = fmaxf(mx, __shfl_xor(mx, 32));
    if (!__all(mx - m_r <= 8.0f)) {
        float mnew = fmaxf(m_r, mx);
        float corr = __expf(m_r - mnew);
        m_r = mnew;
        l_r *= corr;
#pragma unroll
        for (int np = 0; np < 4; ++np) acc[np] = acc[np] * corr;
    }
    float ps = 0.0f;
#pragma unroll
    for (int n = 0; n < 8; ++n)
#pragma unroll
        for (int r = 0; r < 4; ++r) {
            float e = __expf(s[n][r] - m_r);
            s[n][r] = e;
            ps += e;
        }
    l_r += ps;

    bf16x8 pb[4];
#pragma unroll
    for (int n2 = 0; n2 < 4; ++n2)
#pragma unroll
        for (int j = 0; j < 8; ++j)
            pb[n2][j] = f2bb(s[2 * n2 + (j >> 2)][j & 3]);

    int d15 = l16;
    int eoff = (lg & 1) * 4;
#pragma unroll
    for (int n2 = 0; n2 < 4; ++n2) {
        int c0 = (n2 * 4 + (lg >> 1));
        int c1 = c0 + 2;
#pragma unroll
        for (int np = 0; np < 4; ++np) {
            int d = np * 16 + l16;
            union { bf16x8 v; bh4 q[2]; } u;
            u.q[0] = *reinterpret_cast<const bh4*>(&vl[d * 128 + ((c0 ^ d15) << 3) + eoff]);
            u.q[1] = *reinterpret_cast<const bh4*>(&vl[d * 128 + ((c1 ^ d15) << 3) + eoff]);
            acc[np] = __builtin_amdgcn_mfma_f32_16x16x32_bf16(u.v, pb[n2], acc[np], 0, 0, 0);
        }
    }
}

__global__ __launch_bounds__(256) void k_flash(const bf16* __restrict__ Q, const bf16* __restrict__ Kk,
                                               const bf16* __restrict__ Vt, bf16* __restrict__ Out) {
    __shared__ bf16 kl[128 * 64];
    __shared__ bf16 vl[64 * 128];
    int tid = threadIdx.x, lane = tid & 63, w = tid >> 6;
    int l16 = lane & 15, lg = lane >> 4;
    int L = blockIdx.x;
    int xcd = L & 7, m = L >> 3;
    int bh = xcd * 4 + (m & 3);
    int qi = (T_ / 128 - 1) - (m >> 2);
    int q0 = qi * 128;
    int b = bh >> 4, h = bh & 15;
    const bf16* qb = Q + (size_t)bh * T_ * HD_;
    const bf16* kb = Kk + (size_t)bh * T_ * HD_;
    const bf16* vb = Vt + (size_t)bh * HD_ * T_;

    bf16x8 qfr[2][2];
#pragma unroll
    for (int f = 0; f < 2; ++f) {
        int qrow = q0 + w * 32 + f * 16 + l16;
        const bf16* qp = qb + (size_t)qrow * HD_ + lg * 8;
        qfr[f][0] = *reinterpret_cast<const bf16x8*>(qp);
        qfr[f][1] = *reinterpret_cast<const bf16x8*>(qp + 32);
    }
    f32x4 acc[2][4] = {};
    float m_r[2] = {-INFINITY, -INFINITY};
    float l_r[2] = {0.0f, 0.0f};

    for (int kv0 = 0; kv0 <= q0; kv0 += 128) {
        __syncthreads();
#pragma unroll
        for (int i = 0; i < 4; ++i) {
            int idx = i * 256 + tid;
            int kv = idx >> 3, c = idx & 7;
            *reinterpret_cast<bh8*>(&kl[kv * 64 + (((c ^ kv) & 7) << 3)]) =
                *reinterpret_cast<const bh8*>(&kb[(size_t)(kv0 + kv) * HD_ + c * 8]);
        }
#pragma unroll
        for (int i = 0; i < 4; ++i) {
            int idx = i * 256 + tid;
            int d = idx >> 4, c = idx & 15;
            *reinterpret_cast<bh8*>(&vl[d * 128 + (((c ^ d) & 15) << 3)]) =
                *reinterpret_cast<const bh8*>(&vb[(size_t)d * T_ + kv0 + c * 8]);
        }
        __syncthreads();
        if (kv0 == q0) {
#pragma unroll
            for (int f = 0; f < 2; ++f)
                fa3_tile<true>(kl, vl, l16, lg, w * 32 + f * 16 + l16,
                               qfr[f][0], qfr[f][1], acc[f], m_r[f], l_r[f]);
        } else {
#pragma unroll
            for (int f = 0; f < 2; ++f)
                fa3_tile<false>(kl, vl, l16, lg, 0,
                                qfr[f][0], qfr[f][1], acc[f], m_r[f], l_r[f]);
        }
    }
#pragma unroll
    for (int f = 0; f < 2; ++f) {
        float lt = l_r[f];
        lt += __shfl_xor(lt, 16);
        lt += __shfl_xor(lt, 32);
        float inv = 1.0f / lt;
        int qrow = q0 + w * 32 + f * 16 + l16;
#pragma unroll
        for (int np = 0; np < 4; ++np) {
            bh4 o;
#pragma unroll
            for (int r = 0; r < 4; ++r) o.h[r] = f2b(acc[f][np][r] * inv);
            *reinterpret_cast<bh4*>(&Out[(size_t)(b * T_ + qrow) * D_ + h * HD_ + np * 16 + lg * 4]) = o;
        }
    }
}

// ---------------- delta_res (optionally fused with following RMSNorm) ----------------
template <int WRITE_XM>
__global__ __launch_bounds__(256) void k_delta_res(const float* __restrict__ x, const bf16* __restrict__ h,
                                                   const float* __restrict__ gn_w, const float* __restrict__ g_w,
                                                   const float* __restrict__ g_b, const float* __restrict__ wv_w,
                                                   float* __restrict__ out,
                                                   bf16* __restrict__ xm_out, const float* __restrict__ mlp_w) {
    int row = blockIdx.x, tid = threadIdx.x;
    int base = tid * 4;
    float xv[4], hv[4], gnv[4], gwv[4], wvv[4];
    load4f(x + (size_t)row * D_ + base, xv);
    load4f(h + (size_t)row * D_ + base, hv);
    load4f(gn_w + base, gnv);
    load4f(g_w + base, gwv);
    load4f(wv_w + base, wvv);
    float s_h2 = 0, s_x2 = 0, s_xg = 0, s_xv = 0, s_hx = 0;
#pragma unroll
    for (int i = 0; i < 4; ++i) {
        s_h2 += hv[i] * hv[i];
        s_x2 += xv[i] * xv[i];
        s_xg += xv[i] * gnv[i] * gwv[i];
        s_xv += xv[i] * wvv[i];
        s_hx += hv[i] * xv[i];
    }
    s_h2 = waveReduceSum(s_h2); s_x2 = waveReduceSum(s_x2); s_xg = waveReduceSum(s_xg);
    s_xv = waveReduceSum(s_xv); s_hx = waveReduceSum(s_hx);
    __shared__ float red[4][5];
    int wid = tid >> 6;
    if ((tid & 63) == 0) {
        red[wid][0] = s_h2; red[wid][1] = s_x2; red[wid][2] = s_xg;
        red[wid][3] = s_xv; red[wid][4] = s_hx;
    }
    __syncthreads();
    s_h2 = red[0][0] + red[1][0] + red[2][0] + red[3][0];
    s_x2 = red[0][1] + red[1][1] + red[2][1] + red[3][1];
    s_xg = red[0][2] + red[1][2] + red[2][2] + red[3][2];
    s_xv = red[0][3] + red[1][3] + red[2][3] + red[3][3];
    s_hx = red[0][4] + red[1][4] + red[2][4] + red[3][4];

    float r = rsqrtf(s_x2 * (1.0f / D_) + 1e-6f);
    float logit = r * s_xg + g_b[0];
    float beta = 2.0f * sigmoidf_(logit);
    float vsig = sigmoidf_(s_xv);
    float nrm = sqrtf(s_h2);
    float ks = (1.0f / 32.0f) / fmaxf(nrm, 1e-6f);
    float coef = beta * (vsig - ks * s_hx) * ks;
    float o[4];
#pragma unroll
    for (int i = 0; i < 4; ++i) o[i] = xv[i] + coef * hv[i];
    store4(out + (size_t)row * D_ + base, o);

    if (WRITE_XM) {
        float s2 = o[0]*o[0] + o[1]*o[1] + o[2]*o[2] + o[3]*o[3];
        s2 = waveReduceSum(s2);
        __shared__ float red2[4];
        __syncthreads();
        if ((tid & 63) == 0) red2[wid] = s2;
        __syncthreads();
        s2 = red2[0] + red2[1] + red2[2] + red2[3];
        float rr = rsqrtf(s2 * (1.0f / D_) + 1e-6f);
        float mw[4];
        load4f(mlp_w + base, mw);
        bh4 ob;
#pragma unroll
        for (int i = 0; i < 4; ++i) ob.h[i] = f2b(o[i] * rr * mw[i]);
        *reinterpret_cast<bh4*>(xm_out + (size_t)row * D_ + base) = ob;
    }
}

extern "C" void kernel_launch(void* const* d_in, const int* in_sizes, int n_in,
                              void* d_out, int out_size, void* d_ws, size_t ws_size,
                              hipStream_t stream) {
    const float* x       = (const float*)d_in[0];
    const float* wq      = (const float*)d_in[1];
    const float* wk      = (const float*)d_in[2];
    const float* wv      = (const float*)d_in[3];
    const float* wo      = (const float*)d_in[4];
    const float* qn_w    = (const float*)d_in[5];
    const float* kn_w    = (const float*)d_in[6];
    const float* attn_nw = (const float*)d_in[7];
    const float* g1_nw   = (const float*)d_in[8];
    const float* g1_w    = (const float*)d_in[9];
    const float* g1_b    = (const float*)d_in[10];
    const float* wv1     = (const float*)d_in[11];
    const float* mlp_nw  = (const float*)d_in[12];
    const float* w1      = (const float*)d_in[13];
    const float* w2      = (const float*)d_in[14];
    const float* w3      = (const float*)d_in[15];
    const float* g2_nw   = (const float*)d_in[16];
    const float* g2_w    = (const float*)d_in[17];
    const float* g2_b    = (const float*)d_in[18];
    const float* wv2     = (const float*)d_in[19];
    float* out = (float*)d_out;

    char* ws = (char*)d_ws;
    const size_t KB = 1024;
    const size_t MB = 1024 * 1024;
    float* cost = (float*)(ws);                        // 256 KB
    float* sint = (float*)(ws + 256 * KB);             // 256 KB
    bf16* XC = (bf16*)(ws + 512 * KB);                 // 8MB: xc -> wo_bf16 -> xm -> hmlp
    bf16* Bb = (bf16*)(ws + 512 * KB + 8  * MB);       // Bb..Db 24MB: qkv -> attn_out -> wpair/w2b
    bf16* Cb = (bf16*)(ws + 512 * KB + 16 * MB);       // 8MB: h_attn
    bf16* Db = (bf16*)(ws + 512 * KB + 24 * MB);       // 8MB: w2 bf16
    bf16* Eb = (bf16*)(ws + 512 * KB + 32 * MB);       // Eb..Gb 24MB: wqkv -> Qr/Kr/Vt -> g
    bf16* Fb = (bf16*)(ws + 512 * KB + 40 * MB);
    bf16* Gb = (bf16*)(ws + 512 * KB + 48 * MB);
    float* x1 = (float*)(ws + 512 * KB + 56 * MB);     // 16MB f32

    bf16* wqkv = Eb;
    bf16* qkv  = Bb;
    bf16* wbo  = XC;
    bf16* attn_out = Bb;
    bf16* wpair = Bb;
    bf16* w2b  = Db;
    bf16* g    = Eb;
    bf16* hmlp = XC;

    const int nDD = D_ * D_ / 8, nFD = FH_ * D_ / 8;
    dim3 blk(256);

    k_rope_tables<<<dim3((T_ * 32) / 256), blk, 0, stream>>>(cost, sint);

    k_rmsnorm<<<dim3(BT), blk, 0, stream>>>(x, attn_nw, XC);
    k_f2b3<<<dim3((3 * nDD + 255) / 256), blk, 0, stream>>>(wq, wk, wv, wqkv, nDD);

    // fused QKV GEMM: 256x128 tiles, grid (16, 24)
    k_gemm256<0><<<dim3(16, 24), dim3(512), 0, stream>>>(XC, wqkv, qkv, BT, 3 * D_, D_);

    // Q and K norm+rope in one launch; V transpose
    int nbHalf = BT * H_ / 4;
    k_qk_norm_rope2<<<dim3(2 * nbHalf), blk, 0, stream>>>(qkv, qn_w, kn_w, cost, sint, Eb, Fb, nbHalf);
    k_v_transpose<<<dim3(T_ / 64, B_ * H_), blk, 0, stream>>>(qkv, Gb, 3 * D_, 2 * D_);

    k_f2b<<<dim3((nDD + 255) / 256), blk, 0, stream>>>(wo, wbo, nDD);
    k_flash<<<dim3((T_ / 128) * B_ * H_), blk, 0, stream>>>(Eb, Fb, Gb, attn_out);

    // h_attn = attn_out @ wo^T : 128x64 tiles, grid (32, 16)
    k_gemm64<<<dim3(32, 16), blk, 0, stream>>>(attn_out, wbo, Cb, BT, D_, D_);

    // x1 = delta_res(x, h_attn)  (+ fused xm = rmsnorm(x1, mlp_nw) -> XC)
    k_delta_res<1><<<dim3(BT), blk, 0, stream>>>(x, Cb, g1_nw, g1_w, g1_b, wv1, x1, XC, mlp_nw);

    // merged FFN weight conversion (w1/w3 interleaved + w2)
    k_f2b_ffn<<<dim3((3 * nFD + 255) / 256), blk, 0, stream>>>(w1, w3, w2, wpair, w2b, nFD);

    // g = silu(xm@w1^T)*(xm@w3^T): 256x128 tiles, grid (16, 43)
    k_gemm256<1><<<dim3(16, 43), dim3(512), 0, stream>>>(XC, wpair, g, BT, 2 * FH_, D_);

    // h_mlp = g @ w2^T : 128x64, grid (32, 16)
    k_gemm64<<<dim3(32, 16), blk, 0, stream>>>(g, w2b, hmlp, BT, D_, FH_);

    // out = delta_res(x1, h_mlp)
    k_delta_res<0><<<dim3(BT), blk, 0, stream>>>(x1, hmlp, g2_nw, g2_w, g2_b, wv2, out, nullptr, nullptr);
}